// Round 9
// baseline (1057.723 us; speedup 1.0000x reference)
//
#include <hip/hip_runtime.h>
#include <hip/hip_cooperative_groups.h>
#include <hip/hip_bf16.h>
#include <math.h>

namespace cg = cooperative_groups;

namespace {

typedef unsigned long long u64;
typedef __attribute__((ext_vector_type(8))) short bf16x8;
typedef __attribute__((ext_vector_type(4))) float f32x4;

constexpr int KK = 5;
constexpr int K3 = 125;
constexpr int N0 = 16384, E0 = 262144;
constexpr int N1 = 4096,  E1 = 65536;
constexpr int N2 = 1024,  E2 = 16384;
constexpr int N3 = 256,   E3 = 4096;
constexpr int E_TOT = E0 + E1 + E2 + E3;     // 348160
constexpr unsigned ENC_NEG_INF = 0x007FFFFFu;
constexpr int KO2 = K3 * 64, KO3 = K3 * 64, KO4 = K3 * 128;

// ---------------- workspace layout (float-slot offsets) ----------------
constexpr size_t A_PENC1 = 0;
constexpr size_t A_PENC2 = A_PENC1 + (size_t)N1 * 32;
constexpr size_t A_PENC3 = A_PENC2 + (size_t)N2 * 64;
constexpr size_t A_PENC4 = A_PENC3 + (size_t)N3 * 64;
constexpr size_t A_PENC_END = A_PENC4 + (size_t)128 * 128;
constexpr size_t PENC_TOTAL = A_PENC_END;                  // 229376

constexpr size_t A_WT2 = A_PENC_END;
constexpr size_t A_WT3 = A_WT2 + (size_t)K3 * 64 * 32 / 2;
constexpr size_t A_WT4 = A_WT3 + (size_t)K3 * 64 * 64 / 2;

constexpr size_t A_BAS0 = A_WT4 + (size_t)K3 * 128 * 64 / 2;
constexpr size_t A_KID0 = A_BAS0 + (size_t)E0 * 8;
constexpr size_t A_BAS1 = A_KID0 + (size_t)E0 * 2;
constexpr size_t A_KID1 = A_BAS1 + (size_t)E1 * 8;
constexpr size_t A_BAS2 = A_KID1 + (size_t)E1 * 2;
constexpr size_t A_KID2 = A_BAS2 + (size_t)E2 * 8;
constexpr size_t A_BAS3 = A_KID2 + (size_t)E2 * 2;
constexpr size_t A_KID3 = A_BAS3 + (size_t)E3 * 8;

constexpr size_t A_OFF0 = A_KID3 + (size_t)E3 * 2;
constexpr size_t A_OFF1 = A_OFF0 + (N0 + 4);
constexpr size_t A_OFF2 = A_OFF1 + (N1 + 4);
constexpr size_t A_OFF3 = A_OFF2 + (N2 + 4);
constexpr size_t A_CUR0 = A_OFF3 + (N3 + 4);
constexpr size_t A_CUR1 = A_CUR0 + N0;
constexpr size_t A_CUR2 = A_CUR1 + N1;
constexpr size_t A_CUR3 = A_CUR2 + N2;
constexpr size_t A_CUR_END = A_CUR3 + N3;
constexpr size_t CUR_TOTAL = A_CUR_END - A_CUR0;           // 21760
constexpr size_t A_EIX0 = A_CUR_END;
constexpr size_t A_EIX1 = A_EIX0 + E0;
constexpr size_t A_EIX2 = A_EIX1 + E1;
constexpr size_t A_EIX3 = A_EIX2 + E2;
constexpr size_t A_Y = A_EIX3 + E3;
constexpr size_t Y_FLOATS = (size_t)N1 * KO2 / 2;
constexpr size_t A_FCP = A_Y + Y_FLOATS;

constexpr int SMEM_FLOATS = 4128;   // max: W-transpose 32x129

struct P {
    const float *x0, *W1, *root1, *b1, *root2, *b2, *root3, *b3, *root4, *b4;
    const float *ps0, *ps1, *ps2, *ps3;
    const float *W2, *W3, *W4, *fc1w, *fc1b, *fc2w, *fc2b;
    const int *src0, *dst0, *src1, *dst1, *src2, *dst2, *src3, *dst3;
    const int *cl0, *cl1, *cl2, *cl3;
    float* ws;
    float* out;
};

// ---------------- helpers ----------------
__device__ __forceinline__ float eluf(float x) { return x > 0.f ? x : expm1f(x); }

__device__ __forceinline__ unsigned enc_f(float x) {
    unsigned u = __float_as_uint(x);
    return (u & 0x80000000u) ? ~u : (u | 0x80000000u);
}
__device__ __forceinline__ float dec_fin(unsigned u) {
    u = (u & 0x80000000u) ? (u & 0x7fffffffu) : ~u;
    float v = __uint_as_float(u);
    return isfinite(v) ? v : 0.f;
}
__device__ __forceinline__ float bf2f(unsigned short u) {
    return __uint_as_float((unsigned)u << 16);
}
__device__ __forceinline__ unsigned short f2bf(float v) {
    __hip_bfloat16 h = __float2bfloat16(v);
    return *reinterpret_cast<unsigned short*>(&h);
}

__device__ __forceinline__ void decode_edge(const float* __restrict__ pseudo, int e,
                                            float bas[8], int kid[8]) {
    float v0 = pseudo[e * 3 + 0] * (KK - 1);
    float v1 = pseudo[e * 3 + 1] * (KK - 1);
    float v2 = pseudo[e * 3 + 2] * (KK - 1);
    float f0 = fminf(fmaxf(floorf(v0), 0.f), (float)(KK - 2));
    float f1 = fminf(fmaxf(floorf(v1), 0.f), (float)(KK - 2));
    float f2 = fminf(fmaxf(floorf(v2), 0.f), (float)(KK - 2));
    int lo0 = (int)f0, lo1 = (int)f1, lo2 = (int)f2;
    float fr0 = v0 - f0, fr1 = v1 - f1, fr2 = v2 - f2;
#pragma unroll
    for (int c = 0; c < 8; ++c) {
        int b0 = c & 1, b1 = (c >> 1) & 1, b2 = (c >> 2) & 1;
        kid[c] = (lo0 + b0) + (lo1 + b1) * KK + (lo2 + b2) * KK * KK;
        bas[c] = (b0 ? fr0 : 1.f - fr0) * (b1 ? fr1 : 1.f - fr1) * (b2 ? fr2 : 1.f - fr2);
    }
}

// ---------------- ph0: init penc + decode all bases + dst histogram ----------------
__device__ void ph0(const P& p) {
    float* ws = p.ws;
    for (int g = blockIdx.x * 256 + threadIdx.x; g < E_TOT; g += gridDim.x * 256) {
        if (g < (int)PENC_TOTAL) ((unsigned*)(ws + A_PENC1))[g] = ENC_NEG_INF;
        const float* ps; float* bas; u64* kid; int e; const int* dst; int* cur;
        if (g < E0)                { ps = p.ps0; bas = ws + A_BAS0; kid = (u64*)(ws + A_KID0); e = g;                dst = p.dst0; cur = (int*)(ws + A_CUR0); }
        else if (g < E0 + E1)      { ps = p.ps1; bas = ws + A_BAS1; kid = (u64*)(ws + A_KID1); e = g - E0;           dst = p.dst1; cur = (int*)(ws + A_CUR1); }
        else if (g < E0 + E1 + E2) { ps = p.ps2; bas = ws + A_BAS2; kid = (u64*)(ws + A_KID2); e = g - E0 - E1;      dst = p.dst2; cur = (int*)(ws + A_CUR2); }
        else                       { ps = p.ps3; bas = ws + A_BAS3; kid = (u64*)(ws + A_KID3); e = g - E0 - E1 - E2; dst = p.dst3; cur = (int*)(ws + A_CUR3); }
        atomicAdd(&cur[dst[e]], 1);
        float b[8]; int k[8];
        decode_edge(ps, e, b, k);
        *(float4*)(bas + (size_t)e * 8)     = make_float4(b[0], b[1], b[2], b[3]);
        *(float4*)(bas + (size_t)e * 8 + 4) = make_float4(b[4], b[5], b[6], b[7]);
        u64 pk = 0;
#pragma unroll
        for (int c = 0; c < 8; ++c) pk |= (u64)(unsigned)k[c] << (8 * c);
        kid[e] = pk;
    }
}

// ---------------- ph1: exclusive scan per layer (blocks 0..3) ----------------
__device__ void ph1(const P& p, float* smem) {
    float* ws = p.ws;
    if (blockIdx.x < 4) {
        int* ls = (int*)smem;
        int* cur; int* off; int N;
        switch (blockIdx.x) {
            case 0:  cur = (int*)(ws + A_CUR0); off = (int*)(ws + A_OFF0); N = N0; break;
            case 1:  cur = (int*)(ws + A_CUR1); off = (int*)(ws + A_OFF1); N = N1; break;
            case 2:  cur = (int*)(ws + A_CUR2); off = (int*)(ws + A_OFF2); N = N2; break;
            default: cur = (int*)(ws + A_CUR3); off = (int*)(ws + A_OFF3); N = N3; break;
        }
        int t = threadIdx.x;
        int chunk = N >> 8;
        int b0 = t * chunk, b1 = b0 + chunk;
        int s = 0;
        for (int i = b0; i < b1; ++i) s += cur[i];
        ls[t] = s;
        __syncthreads();
        for (int d = 1; d < 256; d <<= 1) {
            int v = (t >= d) ? ls[t - d] : 0;
            __syncthreads();
            ls[t] += v;
            __syncthreads();
        }
        int run = (t == 0) ? 0 : ls[t - 1];
        for (int i = b0; i < b1; ++i) {
            int c = cur[i];
            off[i] = run;
            cur[i] = run;
            run += c;
        }
        if (t == 255) off[N] = run;
    }
}

// ---------------- ph2: csr scatter + W transpose/cast ----------------
__device__ void ph2(const P& p, float* smem) {
    float* ws = p.ws;
    constexpr int NW = 3 * K3;             // 375 transpose units
    constexpr int NS = E_TOT / 256;        // 1360 scatter units
    for (int u = blockIdx.x; u < NW + NS; u += gridDim.x) {
        if (u < NW) {
            const float* W; unsigned short* wt; int IN, OUT, k;
            if (u < K3)          { W = p.W2; wt = (unsigned short*)(ws + A_WT2); IN = 32; OUT = 64;  k = u; }
            else if (u < 2 * K3) { W = p.W3; wt = (unsigned short*)(ws + A_WT3); IN = 64; OUT = 64;  k = u - K3; }
            else                 { W = p.W4; wt = (unsigned short*)(ws + A_WT4); IN = 64; OUT = 128; k = u - 2 * K3; }
            const float* Wk = W + (size_t)k * IN * OUT;
            unsigned short* wk = wt + (size_t)k * IN * OUT;
            int halves = IN / 32;
            for (int h = 0; h < halves; ++h) {
                __syncthreads();
                for (int idx = threadIdx.x; idx < 32 * OUT; idx += 256) {
                    int i2 = idx / OUT, o = idx % OUT;
                    smem[i2 * (OUT + 1) + o] = Wk[(size_t)(h * 32 + i2) * OUT + o];
                }
                __syncthreads();
                for (int idx = threadIdx.x; idx < OUT * 32; idx += 256) {
                    int o = idx / 32, i2 = idx % 32;
                    wk[(size_t)o * IN + h * 32 + i2] = f2bf(smem[i2 * (OUT + 1) + o]);
                }
            }
        } else {
            int g = (u - NW) * 256 + threadIdx.x;
            if (g < E0)                { int q = atomicAdd((int*)(ws + A_CUR0) + p.dst0[g], 1);            ((int*)(ws + A_EIX0))[q] = g; }
            else if (g < E0 + E1)      { int e = g - E0;           int q = atomicAdd((int*)(ws + A_CUR1) + p.dst1[e], 1); ((int*)(ws + A_EIX1))[q] = e; }
            else if (g < E0 + E1 + E2) { int e = g - E0 - E1;      int q = atomicAdd((int*)(ws + A_CUR2) + p.dst2[e], 1); ((int*)(ws + A_EIX2))[q] = e; }
            else                       { int e = g - E0 - E1 - E2; int q = atomicAdd((int*)(ws + A_CUR3) + p.dst3[e], 1); ((int*)(ws + A_EIX3))[q] = e; }
        }
    }
}

// ---------------- ph3: layer-1 agg (half-wave per node, W1 in LDS) ----------------
__device__ void ph3(const P& p, float* smem) {
    float* ws = p.ws;
    float* wlds = smem;
    for (int i = threadIdx.x; i < K3 * 32; i += 256) wlds[i] = p.W1[i];
    __syncthreads();
    const float* bas = ws + A_BAS0;
    const u64* kid = (const u64*)(ws + A_KID0);
    const int* off = (const int*)(ws + A_OFF0);
    const int* eidx = (const int*)(ws + A_EIX0);
    unsigned* penc = (unsigned*)(ws + A_PENC1);
    int o = threadIdx.x & 31;
    int nsub = threadIdx.x >> 5;
    for (int nb = blockIdx.x; nb < N0 / 8; nb += gridDim.x) {
        int n = nb * 8 + nsub;
        int s0 = off[n], s1 = off[n + 1];
        float acc = 0.f;
        int j = s0;
        for (; j + 2 <= s1; j += 2) {
            int ea = eidx[j], eb = eidx[j + 1];
            float4 qa0 = *(const float4*)(bas + (size_t)ea * 8);
            float4 qa1 = *(const float4*)(bas + (size_t)ea * 8 + 4);
            float4 qb0 = *(const float4*)(bas + (size_t)eb * 8);
            float4 qb1 = *(const float4*)(bas + (size_t)eb * 8 + 4);
            u64 ka = kid[ea], kb = kid[eb];
            float xa = p.x0[p.src0[ea]], xb = p.x0[p.src0[eb]];
            float ma, mb;
            ma  = qa0.x * wlds[((int)( ka        & 255u)) * 32 + o];
            ma += qa0.y * wlds[((int)((ka >>  8) & 255u)) * 32 + o];
            ma += qa0.z * wlds[((int)((ka >> 16) & 255u)) * 32 + o];
            ma += qa0.w * wlds[((int)((ka >> 24) & 255u)) * 32 + o];
            ma += qa1.x * wlds[((int)((ka >> 32) & 255u)) * 32 + o];
            ma += qa1.y * wlds[((int)((ka >> 40) & 255u)) * 32 + o];
            ma += qa1.z * wlds[((int)((ka >> 48) & 255u)) * 32 + o];
            ma += qa1.w * wlds[((int)((ka >> 56) & 255u)) * 32 + o];
            mb  = qb0.x * wlds[((int)( kb        & 255u)) * 32 + o];
            mb += qb0.y * wlds[((int)((kb >>  8) & 255u)) * 32 + o];
            mb += qb0.z * wlds[((int)((kb >> 16) & 255u)) * 32 + o];
            mb += qb0.w * wlds[((int)((kb >> 24) & 255u)) * 32 + o];
            mb += qb1.x * wlds[((int)((kb >> 32) & 255u)) * 32 + o];
            mb += qb1.y * wlds[((int)((kb >> 40) & 255u)) * 32 + o];
            mb += qb1.z * wlds[((int)((kb >> 48) & 255u)) * 32 + o];
            mb += qb1.w * wlds[((int)((kb >> 56) & 255u)) * 32 + o];
            acc = fmaf(xa, ma, fmaf(xb, mb, acc));
        }
        if (j < s1) {
            int e = eidx[j];
            float4 q0 = *(const float4*)(bas + (size_t)e * 8);
            float4 q1 = *(const float4*)(bas + (size_t)e * 8 + 4);
            u64 k8 = kid[e];
            float xv = p.x0[p.src0[e]];
            float m;
            m  = q0.x * wlds[((int)( k8        & 255u)) * 32 + o];
            m += q0.y * wlds[((int)((k8 >>  8) & 255u)) * 32 + o];
            m += q0.z * wlds[((int)((k8 >> 16) & 255u)) * 32 + o];
            m += q0.w * wlds[((int)((k8 >> 24) & 255u)) * 32 + o];
            m += q1.x * wlds[((int)((k8 >> 32) & 255u)) * 32 + o];
            m += q1.y * wlds[((int)((k8 >> 40) & 255u)) * 32 + o];
            m += q1.z * wlds[((int)((k8 >> 48) & 255u)) * 32 + o];
            m += q1.w * wlds[((int)((k8 >> 56) & 255u)) * 32 + o];
            acc = fmaf(xv, m, acc);
        }
        float dg = fmaxf((float)(s1 - s0), 1.f);
        float val = acc / dg + p.x0[n] * p.root1[o] + p.b1[o];
        val = eluf(val);
        atomicMax(&penc[(size_t)p.cl0[n] * 32 + o], enc_f(val));
    }
}

// ---------------- ph_gemm: y = x @ W via MFMA, x decoded from encoded pool --------
template <int IN>
__device__ void ph_gemm(const unsigned* __restrict__ penc,
                        const unsigned short* __restrict__ wt,
                        unsigned short* __restrict__ y, int N, int KO) {
    int lane = threadIdx.x & 63;
    int wsub = threadIdx.x >> 6;
    int nTiles = N >> 4;
    int totalU = nTiles * (KO / 64) / 4;
    int l15 = lane & 15;
    int kk = (lane >> 4) << 3;
    int rbase = (lane >> 4) << 2;
    for (int u = blockIdx.x; u < totalU; u += gridDim.x) {
        int wid = u * 4 + wsub;
        int n0 = (wid % nTiles) << 4;
        int ko0 = (wid / nTiles) << 6;
        f32x4 acc[4];
#pragma unroll
        for (int t = 0; t < 4; ++t) acc[t] = (f32x4){0.f, 0.f, 0.f, 0.f};
#pragma unroll
        for (int s = 0; s < IN / 32; ++s) {
            const unsigned* pp = penc + (size_t)(n0 + l15) * IN + s * 32 + kk;
            uint4 u0 = *(const uint4*)pp;
            uint4 u1 = *(const uint4*)(pp + 4);
            unsigned uu[8] = {u0.x, u0.y, u0.z, u0.w, u1.x, u1.y, u1.z, u1.w};
            bf16x8 bfrag;
#pragma unroll
            for (int t = 0; t < 8; ++t) bfrag[t] = (short)f2bf(dec_fin(uu[t]));
#pragma unroll
            for (int t = 0; t < 4; ++t) {
                bf16x8 afrag = *(const bf16x8*)(wt + (size_t)(ko0 + t * 16 + l15) * IN + s * 32 + kk);
                acc[t] = __builtin_amdgcn_mfma_f32_16x16x32_bf16(afrag, bfrag, acc[t], 0, 0, 0);
            }
        }
#pragma unroll
        for (int t = 0; t < 4; ++t) {
            ushort4 sv;
            sv.x = f2bf(acc[t][0]);
            sv.y = f2bf(acc[t][1]);
            sv.z = f2bf(acc[t][2]);
            sv.w = f2bf(acc[t][3]);
            *(ushort4*)(y + (size_t)(n0 + l15) * KO + ko0 + t * 16 + rbase) = sv;
        }
    }
}

// ---------------- ph_gather: wave-per-node gather+agg+finish+pool ----------------
template <int IN, int OUT>
__device__ void ph_gather(const unsigned short* __restrict__ y,
                          const float* __restrict__ bas,
                          const u64* __restrict__ kid,
                          const int* __restrict__ src,
                          const int* __restrict__ off,
                          const int* __restrict__ eidx,
                          const unsigned* __restrict__ penc_prev,
                          const float* __restrict__ root,
                          const float* __restrict__ bias,
                          const int* __restrict__ cl,
                          unsigned* __restrict__ penc, int N) {
    constexpr int KO = K3 * OUT;
    constexpr int WPT = OUT / 64;
    int lane = threadIdx.x & 63;
    int wv = threadIdx.x >> 6;
    for (int u = blockIdx.x; u < N / 4; u += gridDim.x) {
        int n = u * 4 + wv;
        int s0 = off[n], s1 = off[n + 1];
        float acc0 = 0.f, acc1 = 0.f;
        int j = s0;
        for (; j + 2 <= s1; j += 2) {
            int ea = eidx[j], eb = eidx[j + 1];
            float4 qa0 = *(const float4*)(bas + (size_t)ea * 8);
            float4 qa1 = *(const float4*)(bas + (size_t)ea * 8 + 4);
            float4 qb0 = *(const float4*)(bas + (size_t)eb * 8);
            float4 qb1 = *(const float4*)(bas + (size_t)eb * 8 + 4);
            u64 ka = kid[ea], kb = kid[eb];
            const unsigned short* ypa = y + (size_t)src[ea] * KO + lane;
            const unsigned short* ypb = y + (size_t)src[eb] * KO + lane;
            float ba[8] = {qa0.x, qa0.y, qa0.z, qa0.w, qa1.x, qa1.y, qa1.z, qa1.w};
            float bb[8] = {qb0.x, qb0.y, qb0.z, qb0.w, qb1.x, qb1.y, qb1.z, qb1.w};
            float va[8], vb[8], va2[8], vb2[8];
#pragma unroll
            for (int c = 0; c < 8; ++c) {
                int kca = (int)((ka >> (8 * c)) & 255u);
                int kcb = (int)((kb >> (8 * c)) & 255u);
                va[c] = bf2f(ypa[(size_t)kca * OUT]);
                vb[c] = bf2f(ypb[(size_t)kcb * OUT]);
                if (WPT == 2) {
                    va2[c] = bf2f(ypa[(size_t)kca * OUT + 64]);
                    vb2[c] = bf2f(ypb[(size_t)kcb * OUT + 64]);
                }
            }
#pragma unroll
            for (int c = 0; c < 8; ++c) {
                acc0 = fmaf(ba[c], va[c], acc0);
                acc0 = fmaf(bb[c], vb[c], acc0);
                if (WPT == 2) {
                    acc1 = fmaf(ba[c], va2[c], acc1);
                    acc1 = fmaf(bb[c], vb2[c], acc1);
                }
            }
        }
        if (j < s1) {
            int e = eidx[j];
            float4 q0 = *(const float4*)(bas + (size_t)e * 8);
            float4 q1 = *(const float4*)(bas + (size_t)e * 8 + 4);
            u64 k8 = kid[e];
            const unsigned short* yp = y + (size_t)src[e] * KO + lane;
            float b[8] = {q0.x, q0.y, q0.z, q0.w, q1.x, q1.y, q1.z, q1.w};
#pragma unroll
            for (int c = 0; c < 8; ++c) {
                int kc = (int)((k8 >> (8 * c)) & 255u);
                acc0 = fmaf(b[c], bf2f(yp[(size_t)kc * OUT]), acc0);
                if (WPT == 2) acc1 = fmaf(b[c], bf2f(yp[(size_t)kc * OUT + 64]), acc1);
            }
        }
        float dg = fmaxf((float)(s1 - s0), 1.f);
        float accs[2] = {acc0, acc1};
#pragma unroll
        for (int w = 0; w < WPT; ++w) {
            int o = lane + 64 * w;
            float r = 0.f;
            for (int i = 0; i < IN; ++i)
                r = fmaf(dec_fin(penc_prev[(size_t)n * IN + i]), root[(size_t)i * OUT + o], r);
            float val = accs[w] / dg + r + bias[o];
            val = eluf(val);
            atomicMax(&penc[(size_t)cl[n] * OUT + o], enc_f(val));
        }
    }
}

// ---------------- ph10: fc1 partials ----------------
__device__ void ph10(const P& p, float* smem) {
    float* ws = p.ws;
    const unsigned* penc4 = (const unsigned*)(ws + A_PENC4);
    float* part = ws + A_FCP;
    for (int u = blockIdx.x; u < 256; u += gridDim.x) {
        __syncthreads();
        int ks = u & 15, bq = u >> 4;
        int t = threadIdx.x;
        if (t < 64) smem[t] = dec_fin(penc4[(size_t)bq * 1024 + ks * 64 + t]);
        __syncthreads();
        const float* wp = p.fc1w + (size_t)(ks * 64) * 256 + t;
        float acc = 0.f;
#pragma unroll 8
        for (int k = 0; k < 64; ++k)
            acc = fmaf(smem[k], wp[(size_t)k * 256], acc);
        part[((size_t)bq * 16 + ks) * 256 + t] = acc;
    }
}

// ---------------- ph11: reduce + ELU + fc2 + log_softmax ----------------
__device__ void ph11(const P& p, float* smem) {
    float* ws = p.ws;
    const float* part = ws + A_FCP;
    float* h = smem;
    float* l = smem + 256;
    float* red = smem + 266;
    for (int u = blockIdx.x; u < 16; u += gridDim.x) {
        __syncthreads();
        int t = threadIdx.x;
        const float* pp = part + (size_t)u * 16 * 256 + t;
        float acc = p.fc1b[t];
#pragma unroll
        for (int ks = 0; ks < 16; ++ks) acc += pp[ks * 256];
        h[t] = eluf(acc);
        __syncthreads();
        if (t < 10) {
            float a2 = p.fc2b[t];
            for (int q = 0; q < 256; ++q)
                a2 = fmaf(h[q], p.fc2w[(size_t)q * 10 + t], a2);
            l[t] = a2;
        }
        __syncthreads();
        if (t == 0) {
            float m = l[0];
            for (int i = 1; i < 10; ++i) m = fmaxf(m, l[i]);
            float s = 0.f;
            for (int i = 0; i < 10; ++i) s += expf(l[i] - m);
            red[0] = m;
            red[1] = logf(s);
        }
        __syncthreads();
        if (t < 10) p.out[(size_t)u * 10 + t] = l[t] - red[0] - red[1];
    }
}

// ---------------- the cooperative mega-kernel ----------------
__global__ __launch_bounds__(256, 4) void mega(P p) {
    __shared__ float smem[SMEM_FLOATS];
    cg::grid_group grid = cg::this_grid();
    float* ws = p.ws;
    unsigned* penc1 = (unsigned*)(ws + A_PENC1);
    unsigned* penc2 = (unsigned*)(ws + A_PENC2);
    unsigned* penc3 = (unsigned*)(ws + A_PENC3);
    unsigned* penc4 = (unsigned*)(ws + A_PENC4);
    unsigned short* yb = (unsigned short*)(ws + A_Y);

    ph0(p);                     grid.sync();
    ph1(p, smem);               grid.sync();
    ph2(p, smem);               grid.sync();
    ph3(p, smem);               grid.sync();
    ph_gemm<32>(penc1, (unsigned short*)(ws + A_WT2), yb, N1, KO2);  grid.sync();
    ph_gather<32, 64>(yb, ws + A_BAS1, (u64*)(ws + A_KID1), p.src1,
                      (int*)(ws + A_OFF1), (int*)(ws + A_EIX1),
                      penc1, p.root2, p.b2, p.cl1, penc2, N1);       grid.sync();
    ph_gemm<64>(penc2, (unsigned short*)(ws + A_WT3), yb, N2, KO3);  grid.sync();
    ph_gather<64, 64>(yb, ws + A_BAS2, (u64*)(ws + A_KID2), p.src2,
                      (int*)(ws + A_OFF2), (int*)(ws + A_EIX2),
                      penc2, p.root3, p.b3, p.cl2, penc3, N2);       grid.sync();
    ph_gemm<64>(penc3, (unsigned short*)(ws + A_WT4), yb, N3, KO4);  grid.sync();
    ph_gather<64, 128>(yb, ws + A_BAS3, (u64*)(ws + A_KID3), p.src3,
                       (int*)(ws + A_OFF3), (int*)(ws + A_EIX3),
                       penc3, p.root4, p.b4, p.cl3, penc4, N3);      grid.sync();
    ph10(p, smem);              grid.sync();
    ph11(p, smem);
}

// ---------------- sequential fallback wrappers ----------------
__global__ __launch_bounds__(256) void k_ph0(P p)  { ph0(p); }
__global__ __launch_bounds__(256) void k_ph1(P p)  { __shared__ float s[SMEM_FLOATS]; ph1(p, s); }
__global__ __launch_bounds__(256) void k_ph2(P p)  { __shared__ float s[SMEM_FLOATS]; ph2(p, s); }
__global__ __launch_bounds__(256) void k_ph3(P p)  { __shared__ float s[SMEM_FLOATS]; ph3(p, s); }
__global__ __launch_bounds__(256) void k_gemm2(P p) {
    ph_gemm<32>((unsigned*)(p.ws + A_PENC1), (unsigned short*)(p.ws + A_WT2),
                (unsigned short*)(p.ws + A_Y), N1, KO2);
}
__global__ __launch_bounds__(256) void k_gath2(P p) {
    ph_gather<32, 64>((unsigned short*)(p.ws + A_Y), p.ws + A_BAS1, (u64*)(p.ws + A_KID1), p.src1,
                      (int*)(p.ws + A_OFF1), (int*)(p.ws + A_EIX1),
                      (unsigned*)(p.ws + A_PENC1), p.root2, p.b2, p.cl1,
                      (unsigned*)(p.ws + A_PENC2), N1);
}
__global__ __launch_bounds__(256) void k_gemm3(P p) {
    ph_gemm<64>((unsigned*)(p.ws + A_PENC2), (unsigned short*)(p.ws + A_WT3),
                (unsigned short*)(p.ws + A_Y), N2, KO3);
}
__global__ __launch_bounds__(256) void k_gath3(P p) {
    ph_gather<64, 64>((unsigned short*)(p.ws + A_Y), p.ws + A_BAS2, (u64*)(p.ws + A_KID2), p.src2,
                      (int*)(p.ws + A_OFF2), (int*)(p.ws + A_EIX2),
                      (unsigned*)(p.ws + A_PENC2), p.root3, p.b3, p.cl2,
                      (unsigned*)(p.ws + A_PENC3), N2);
}
__global__ __launch_bounds__(256) void k_gemm4(P p) {
    ph_gemm<64>((unsigned*)(p.ws + A_PENC3), (unsigned short*)(p.ws + A_WT4),
                (unsigned short*)(p.ws + A_Y), N3, KO4);
}
__global__ __launch_bounds__(256) void k_gath4(P p) {
    ph_gather<64, 128>((unsigned short*)(p.ws + A_Y), p.ws + A_BAS3, (u64*)(p.ws + A_KID3), p.src3,
                       (int*)(p.ws + A_OFF3), (int*)(p.ws + A_EIX3),
                       (unsigned*)(p.ws + A_PENC3), p.root4, p.b4, p.cl3,
                       (unsigned*)(p.ws + A_PENC4), N3);
}
__global__ __launch_bounds__(256) void k_ph10(P p) { __shared__ float s[SMEM_FLOATS]; ph10(p, s); }
__global__ __launch_bounds__(256) void k_ph11(P p) { __shared__ float s[SMEM_FLOATS]; ph11(p, s); }

} // namespace

extern "C" void kernel_launch(void* const* d_in, const int* in_sizes, int n_in,
                              void* d_out, int out_size, void* d_ws, size_t ws_size,
                              hipStream_t stream) {
    P p;
    p.x0    = (const float*)d_in[0];
    p.ps0   = (const float*)d_in[1];
    p.ps1   = (const float*)d_in[2];
    p.ps2   = (const float*)d_in[3];
    p.ps3   = (const float*)d_in[4];
    p.W1    = (const float*)d_in[5];
    p.root1 = (const float*)d_in[6];
    p.b1    = (const float*)d_in[7];
    p.W2    = (const float*)d_in[8];
    p.root2 = (const float*)d_in[9];
    p.b2    = (const float*)d_in[10];
    p.W3    = (const float*)d_in[11];
    p.root3 = (const float*)d_in[12];
    p.b3    = (const float*)d_in[13];
    p.W4    = (const float*)d_in[14];
    p.root4 = (const float*)d_in[15];
    p.b4    = (const float*)d_in[16];
    p.fc1w  = (const float*)d_in[17];
    p.fc1b  = (const float*)d_in[18];
    p.fc2w  = (const float*)d_in[19];
    p.fc2b  = (const float*)d_in[20];
    p.src0 = (const int*)d_in[21];
    p.dst0 = (const int*)d_in[22];
    p.src1 = (const int*)d_in[23];
    p.dst1 = (const int*)d_in[24];
    p.src2 = (const int*)d_in[25];
    p.dst2 = (const int*)d_in[26];
    p.src3 = (const int*)d_in[27];
    p.dst3 = (const int*)d_in[28];
    p.cl0  = (const int*)d_in[29];
    p.cl1  = (const int*)d_in[30];
    p.cl2  = (const int*)d_in[31];
    p.cl3  = (const int*)d_in[32];
    p.ws = (float*)d_ws;
    p.out = (float*)d_out;

    // zero CSR cursors (hist accumulates into them in ph0)
    hipMemsetAsync(p.ws + A_CUR0, 0, CUR_TOTAL * sizeof(int), stream);

    // try the cooperative mega-kernel; fall back to sequential dispatches
    bool done = false;
    int dev = 0;
    if (hipGetDevice(&dev) == hipSuccess) {
        int coop = 0, cus = 0, perCU = 0;
        (void)hipDeviceGetAttribute(&coop, hipDeviceAttributeCooperativeLaunch, dev);
        (void)hipDeviceGetAttribute(&cus, hipDeviceAttributeMultiprocessorCount, dev);
        (void)hipOccupancyMaxActiveBlocksPerMultiprocessor(&perCU, mega, 256, 0);
        if (coop && cus > 0 && perCU > 0) {
            long long g = (long long)perCU * cus;
            int grid = (int)(g > 2048 ? 2048 : g);
            if (grid >= 16) {
                void* args[] = {(void*)&p};
                if (hipLaunchCooperativeKernel(mega, dim3(grid), dim3(256),
                                               args, 0, stream) == hipSuccess)
                    done = true;
            }
        }
    }
    if (!done) {
        k_ph0<<<(E_TOT + 255) / 256, 256, 0, stream>>>(p);
        k_ph1<<<4, 256, 0, stream>>>(p);
        k_ph2<<<3 * K3 + E_TOT / 256, 256, 0, stream>>>(p);
        k_ph3<<<N0 / 8, 256, 0, stream>>>(p);
        k_gemm2<<<(N1 / 16) * (KO2 / 64) / 4, 256, 0, stream>>>(p);
        k_gath2<<<N1 / 4, 256, 0, stream>>>(p);
        k_gemm3<<<(N2 / 16) * (KO3 / 64) / 4, 256, 0, stream>>>(p);
        k_gath3<<<N2 / 4, 256, 0, stream>>>(p);
        k_gemm4<<<(N3 / 16) * (KO4 / 64) / 4, 256, 0, stream>>>(p);
        k_gath4<<<N3 / 4, 256, 0, stream>>>(p);
        k_ph10<<<256, 256, 0, stream>>>(p);
        k_ph11<<<16, 256, 0, stream>>>(p);
    }
}

// Round 10
// 345.692 us; speedup vs baseline: 3.0597x; 3.0597x over previous
//
#include <hip/hip_runtime.h>
#include <hip/hip_bf16.h>
#include <math.h>

namespace {

typedef unsigned long long u64;
typedef __attribute__((ext_vector_type(8))) short bf16x8;
typedef __attribute__((ext_vector_type(4))) float f32x4;

constexpr int KK = 5;
constexpr int K3 = 125;
constexpr int N0 = 16384, E0 = 262144;
constexpr int N1 = 4096,  E1 = 65536;
constexpr int N2 = 1024,  E2 = 16384;
constexpr int N3 = 256,   E3 = 4096;
constexpr int E_TOT = E0 + E1 + E2 + E3;     // 348160
constexpr unsigned ENC_NEG_INF = 0x007FFFFFu;
constexpr int KO2 = K3 * 64, KO3 = K3 * 64, KO4 = K3 * 128;

// ---------------- workspace layout (float-slot offsets) ----------------
constexpr size_t A_PENC1 = 0;
constexpr size_t A_PENC2 = A_PENC1 + (size_t)N1 * 32;
constexpr size_t A_PENC3 = A_PENC2 + (size_t)N2 * 64;
constexpr size_t A_PENC4 = A_PENC3 + (size_t)N3 * 64;
constexpr size_t A_PENC_END = A_PENC4 + (size_t)128 * 128;
constexpr size_t PENC_TOTAL = A_PENC_END;                  // 229376

constexpr size_t A_WT2 = A_PENC_END;
constexpr size_t A_WT3 = A_WT2 + (size_t)K3 * 64 * 32 / 2;
constexpr size_t A_WT4 = A_WT3 + (size_t)K3 * 64 * 64 / 2;

constexpr size_t A_OFF0 = A_WT4 + (size_t)K3 * 128 * 64 / 2;
constexpr size_t A_OFF1 = A_OFF0 + (N0 + 4);
constexpr size_t A_OFF2 = A_OFF1 + (N1 + 4);
constexpr size_t A_OFF3 = A_OFF2 + (N2 + 4);
constexpr size_t A_CUR0 = A_OFF3 + (N3 + 4);
constexpr size_t A_CUR1 = A_CUR0 + N0;
constexpr size_t A_CUR2 = A_CUR1 + N1;
constexpr size_t A_CUR3 = A_CUR2 + N2;
constexpr size_t A_CUR_END = A_CUR3 + N3;
constexpr size_t CUR_TOTAL = A_CUR_END - A_CUR0;           // 21760

constexpr size_t A_REC0 = (A_CUR_END + 3) & ~(size_t)3;    // 12 floats (48B) per edge
constexpr size_t A_REC1 = A_REC0 + (size_t)E0 * 12;
constexpr size_t A_REC2 = A_REC1 + (size_t)E1 * 12;
constexpr size_t A_REC3 = A_REC2 + (size_t)E2 * 12;
constexpr size_t A_Y    = (A_REC3 + (size_t)E3 * 12 + 3) & ~(size_t)3;

// grid partition constants
constexpr int NB_HIST  = (E_TOT + 255) / 256;  // 1360
constexpr int NB_SCAT0 = E0 / 256;             // 1024
constexpr int NB_SCAT1 = E1 / 256;             // 256
constexpr int NB_SCAT2 = E2 / 256;             // 64
constexpr int NB_SCAT3 = E3 / 256;             // 16
constexpr int NB_L1    = N0 / 8;               // 2048
constexpr int NB_GEMM2 = (N1 / 16) * (KO2 / 64) / 4;   // 8000
constexpr int NB_GEMM3 = (N2 / 16) * (KO3 / 64) / 4;   // 2000
constexpr int NB_GEMM4 = (N3 / 16) * (KO4 / 64) / 4;   // 1000
constexpr int NB_GA2   = N1 / 4;               // 1024
constexpr int NB_GA3   = N2 / 4;               // 256
constexpr int NB_GA4   = N3 / 4;               // 64

struct __align__(16) ERec {      // one CSR-ordered edge record (48 B)
    float4 q0;
    float4 q1;
    u64 kid;
    unsigned src;
    unsigned pad;
};

struct P {
    const float *x0, *W1, *root1, *b1, *root2, *b2, *root3, *b3, *root4, *b4;
    const float *ps0, *ps1, *ps2, *ps3;
    const float *W2, *W3, *W4, *fc1w, *fc1b, *fc2w, *fc2b;
    const int *src0, *dst0, *src1, *dst1, *src2, *dst2, *src3, *dst3;
    const int *cl0, *cl1, *cl2, *cl3;
    float* ws;
    float* out;
};

// ---------------- helpers ----------------
__device__ __forceinline__ float eluf(float x) { return x > 0.f ? x : expm1f(x); }

__device__ __forceinline__ unsigned enc_f(float x) {
    unsigned u = __float_as_uint(x);
    return (u & 0x80000000u) ? ~u : (u | 0x80000000u);
}
__device__ __forceinline__ float dec_fin(unsigned u) {
    u = (u & 0x80000000u) ? (u & 0x7fffffffu) : ~u;
    float v = __uint_as_float(u);
    return isfinite(v) ? v : 0.f;
}
__device__ __forceinline__ float bf2f(unsigned short u) {
    return __uint_as_float((unsigned)u << 16);
}
__device__ __forceinline__ unsigned short f2bf(float v) {
    __hip_bfloat16 h = __float2bfloat16(v);
    return *reinterpret_cast<unsigned short*>(&h);
}

__device__ __forceinline__ void decode_edge(const float* __restrict__ pseudo, int e,
                                            float bas[8], int kid[8]) {
    float v0 = pseudo[e * 3 + 0] * (KK - 1);
    float v1 = pseudo[e * 3 + 1] * (KK - 1);
    float v2 = pseudo[e * 3 + 2] * (KK - 1);
    float f0 = fminf(fmaxf(floorf(v0), 0.f), (float)(KK - 2));
    float f1 = fminf(fmaxf(floorf(v1), 0.f), (float)(KK - 2));
    float f2 = fminf(fmaxf(floorf(v2), 0.f), (float)(KK - 2));
    int lo0 = (int)f0, lo1 = (int)f1, lo2 = (int)f2;
    float fr0 = v0 - f0, fr1 = v1 - f1, fr2 = v2 - f2;
#pragma unroll
    for (int c = 0; c < 8; ++c) {
        int b0 = c & 1, b1 = (c >> 1) & 1, b2 = (c >> 2) & 1;
        kid[c] = (lo0 + b0) + (lo1 + b1) * KK + (lo2 + b2) * KK * KK;
        bas[c] = (b0 ? fr0 : 1.f - fr0) * (b1 ? fr1 : 1.f - fr1) * (b2 ? fr2 : 1.f - fr2);
    }
}

// ---------------- unit: W[k][i][o] f32 -> wt[(k*OUT+o)][i] bf16 (32-row halves) ----
__device__ void wt_unit(const float* __restrict__ W, unsigned short* __restrict__ wt,
                        int IN, int OUT, int k, float* smem) {
    const float* Wk = W + (size_t)k * IN * OUT;
    unsigned short* wk = wt + (size_t)k * IN * OUT;
    int halves = IN / 32;
    for (int h = 0; h < halves; ++h) {
        __syncthreads();
        for (int idx = threadIdx.x; idx < 32 * OUT; idx += 256) {
            int i = idx / OUT, o = idx % OUT;
            smem[i * (OUT + 1) + o] = Wk[(size_t)(h * 32 + i) * OUT + o];
        }
        __syncthreads();
        for (int idx = threadIdx.x; idx < OUT * 32; idx += 256) {
            int o = idx / 32, i = idx % 32;
            wk[(size_t)o * IN + h * 32 + i] = f2bf(smem[i * (OUT + 1) + o]);
        }
    }
}

// ---------------- unit: decode + scatter one 256-edge slab into CSR records -------
__device__ void scat_unit(int u, const float* __restrict__ ps,
                          const int* __restrict__ dst, const int* __restrict__ srcA,
                          int* __restrict__ cur, ERec* __restrict__ rec, int E) {
    int e = u * 256 + threadIdx.x;
    if (e >= E) return;
    float b[8]; int k[8];
    decode_edge(ps, e, b, k);
    u64 pk = 0;
#pragma unroll
    for (int c = 0; c < 8; ++c) pk |= (u64)(unsigned)k[c] << (8 * c);
    int q = atomicAdd(&cur[dst[e]], 1);
    ERec r;
    r.q0 = make_float4(b[0], b[1], b[2], b[3]);
    r.q1 = make_float4(b[4], b[5], b[6], b[7]);
    r.kid = pk;
    r.src = (unsigned)srcA[e];
    r.pad = 0;
    rec[q] = r;
}

// ---------------- unit: one MFMA tile-group of y = x @ W ----------------
template <int IN>
__device__ void gemm_unit(int u, const unsigned* __restrict__ penc,
                          const unsigned short* __restrict__ wt,
                          unsigned short* __restrict__ y, int N, int KO) {
    int lane = threadIdx.x & 63;
    int wsub = threadIdx.x >> 6;
    int nTiles = N >> 4;
    int wid = u * 4 + wsub;
    int n0 = (wid % nTiles) << 4;
    int ko0 = (wid / nTiles) << 6;
    int l15 = lane & 15;
    int kk = (lane >> 4) << 3;
    int rbase = (lane >> 4) << 2;
    f32x4 acc[4];
#pragma unroll
    for (int t = 0; t < 4; ++t) acc[t] = (f32x4){0.f, 0.f, 0.f, 0.f};
#pragma unroll
    for (int s = 0; s < IN / 32; ++s) {
        const unsigned* pp = penc + (size_t)(n0 + l15) * IN + s * 32 + kk;
        uint4 u0 = *(const uint4*)pp;
        uint4 u1 = *(const uint4*)(pp + 4);
        unsigned uu[8] = {u0.x, u0.y, u0.z, u0.w, u1.x, u1.y, u1.z, u1.w};
        bf16x8 bfrag;
#pragma unroll
        for (int t = 0; t < 8; ++t) bfrag[t] = (short)f2bf(dec_fin(uu[t]));
#pragma unroll
        for (int t = 0; t < 4; ++t) {
            bf16x8 afrag = *(const bf16x8*)(wt + (size_t)(ko0 + t * 16 + l15) * IN + s * 32 + kk);
            acc[t] = __builtin_amdgcn_mfma_f32_16x16x32_bf16(afrag, bfrag, acc[t], 0, 0, 0);
        }
    }
#pragma unroll
    for (int t = 0; t < 4; ++t) {
        ushort4 sv;
        sv.x = f2bf(acc[t][0]);
        sv.y = f2bf(acc[t][1]);
        sv.z = f2bf(acc[t][2]);
        sv.w = f2bf(acc[t][3]);
        *(ushort4*)(y + (size_t)(n0 + l15) * KO + ko0 + t * 16 + rbase) = sv;
    }
}

// ---------------- unit: 4 nodes of gather+agg+finish+pool (CSR stream) -----------
template <int IN, int OUT>
__device__ void gather_unit(int u, const unsigned short* __restrict__ y,
                            const ERec* __restrict__ rec, const int* __restrict__ off,
                            const unsigned* __restrict__ penc_prev,
                            const float* __restrict__ root,
                            const float* __restrict__ bias,
                            const int* __restrict__ cl,
                            unsigned* __restrict__ penc) {
    constexpr int KO = K3 * OUT;
    constexpr int WPT = OUT / 64;
    int lane = threadIdx.x & 63;
    int wv = threadIdx.x >> 6;
    int n = u * 4 + wv;
    int s0 = off[n], s1 = off[n + 1];
    float acc0 = 0.f, acc1 = 0.f;
    int j = s0;
    for (; j + 2 <= s1; j += 2) {
        ERec ra = rec[j], rb = rec[j + 1];
        const unsigned short* ypa = y + (size_t)ra.src * KO + lane;
        const unsigned short* ypb = y + (size_t)rb.src * KO + lane;
        float ba[8] = {ra.q0.x, ra.q0.y, ra.q0.z, ra.q0.w, ra.q1.x, ra.q1.y, ra.q1.z, ra.q1.w};
        float bb[8] = {rb.q0.x, rb.q0.y, rb.q0.z, rb.q0.w, rb.q1.x, rb.q1.y, rb.q1.z, rb.q1.w};
        u64 ka = ra.kid, kb = rb.kid;
        float va[8], vb[8], va2[8], vb2[8];
#pragma unroll
        for (int c = 0; c < 8; ++c) {
            int kca = (int)((ka >> (8 * c)) & 255u);
            int kcb = (int)((kb >> (8 * c)) & 255u);
            va[c] = bf2f(ypa[(size_t)kca * OUT]);
            vb[c] = bf2f(ypb[(size_t)kcb * OUT]);
            if (WPT == 2) {
                va2[c] = bf2f(ypa[(size_t)kca * OUT + 64]);
                vb2[c] = bf2f(ypb[(size_t)kcb * OUT + 64]);
            }
        }
#pragma unroll
        for (int c = 0; c < 8; ++c) {
            acc0 = fmaf(ba[c], va[c], acc0);
            acc0 = fmaf(bb[c], vb[c], acc0);
            if (WPT == 2) {
                acc1 = fmaf(ba[c], va2[c], acc1);
                acc1 = fmaf(bb[c], vb2[c], acc1);
            }
        }
    }
    if (j < s1) {
        ERec r = rec[j];
        const unsigned short* yp = y + (size_t)r.src * KO + lane;
        float b[8] = {r.q0.x, r.q0.y, r.q0.z, r.q0.w, r.q1.x, r.q1.y, r.q1.z, r.q1.w};
        u64 k8 = r.kid;
#pragma unroll
        for (int c = 0; c < 8; ++c) {
            int kc = (int)((k8 >> (8 * c)) & 255u);
            acc0 = fmaf(b[c], bf2f(yp[(size_t)kc * OUT]), acc0);
            if (WPT == 2) acc1 = fmaf(b[c], bf2f(yp[(size_t)kc * OUT + 64]), acc1);
        }
    }
    float dg = fmaxf((float)(s1 - s0), 1.f);
    float accs[2] = {acc0, acc1};
#pragma unroll
    for (int w = 0; w < WPT; ++w) {
        int o = lane + 64 * w;
        float r = 0.f;
        for (int i = 0; i < IN; ++i)
            r = fmaf(dec_fin(penc_prev[(size_t)n * IN + i]), root[(size_t)i * OUT + o], r);
        float val = accs[w] / dg + r + bias[o];
        val = eluf(val);
        atomicMax(&penc[(size_t)cl[n] * OUT + o], enc_f(val));
    }
}

// ================= kernels =================

// K1: init penc + dst histogram (+ W2 transpose in tail blocks)
__global__ __launch_bounds__(256) void k_p1(P p) {
    __shared__ float smem[32 * 129];
    float* ws = p.ws;
    int bid = blockIdx.x;
    if (bid < NB_HIST) {
        int g = bid * 256 + threadIdx.x;
        if (g < (int)PENC_TOTAL) ((unsigned*)(ws + A_PENC1))[g] = ENC_NEG_INF;
        if (g >= E_TOT) return;
        const int* dst; int* cur; int e;
        if (g < E0)                { dst = p.dst0; cur = (int*)(ws + A_CUR0); e = g; }
        else if (g < E0 + E1)      { dst = p.dst1; cur = (int*)(ws + A_CUR1); e = g - E0; }
        else if (g < E0 + E1 + E2) { dst = p.dst2; cur = (int*)(ws + A_CUR2); e = g - E0 - E1; }
        else                       { dst = p.dst3; cur = (int*)(ws + A_CUR3); e = g - E0 - E1 - E2; }
        atomicAdd(&cur[dst[e]], 1);
    } else {
        wt_unit(p.W2, (unsigned short*)(ws + A_WT2), 32, 64, bid - NB_HIST, smem);
    }
}

// K2: exclusive scan per layer
__global__ __launch_bounds__(1024) void k_scan(P p) {
    __shared__ int ls[1024];
    float* ws = p.ws;
    int* cur; int* off; int N;
    switch (blockIdx.x) {
        case 0:  cur = (int*)(ws + A_CUR0); off = (int*)(ws + A_OFF0); N = N0; break;
        case 1:  cur = (int*)(ws + A_CUR1); off = (int*)(ws + A_OFF1); N = N1; break;
        case 2:  cur = (int*)(ws + A_CUR2); off = (int*)(ws + A_OFF2); N = N2; break;
        default: cur = (int*)(ws + A_CUR3); off = (int*)(ws + A_OFF3); N = N3; break;
    }
    int t = threadIdx.x;
    int chunk = (N + 1023) >> 10;
    int b0 = t * chunk;
    int b1 = min(b0 + chunk, N);
    int s = 0;
    for (int i = b0; i < b1; ++i) s += cur[i];
    ls[t] = s;
    __syncthreads();
    for (int d = 1; d < 1024; d <<= 1) {
        int v = (t >= d) ? ls[t - d] : 0;
        __syncthreads();
        ls[t] += v;
        __syncthreads();
    }
    int run = (t == 0) ? 0 : ls[t - 1];
    for (int i = b0; i < b1; ++i) {
        int c = cur[i];
        off[i] = run;
        cur[i] = run;
        run += c;
    }
    if (t == 1023) off[N] = run;
}

// K3: scatter-decode layer-0 edges into CSR records
__global__ __launch_bounds__(256) void k_p2(P p) {
    scat_unit(blockIdx.x, p.ps0, p.dst0, p.src0,
              (int*)(p.ws + A_CUR0), (ERec*)(p.ws + A_REC0), E0);
}

// K4: layer-1 aggregation (+ layer-1 edge scatter in tail blocks)
__global__ __launch_bounds__(256) void k_l1(P p) {
    __shared__ float wlds[K3 * 32];
    float* ws = p.ws;
    int bid = blockIdx.x;
    if (bid >= NB_L1) {
        scat_unit(bid - NB_L1, p.ps1, p.dst1, p.src1,
                  (int*)(ws + A_CUR1), (ERec*)(ws + A_REC1), E1);
        return;
    }
    for (int i = threadIdx.x; i < K3 * 32; i += 256) wlds[i] = p.W1[i];
    __syncthreads();
    const ERec* rec = (const ERec*)(ws + A_REC0);
    const int* off = (const int*)(ws + A_OFF0);
    unsigned* penc = (unsigned*)(ws + A_PENC1);
    int o = threadIdx.x & 31;
    int nsub = threadIdx.x >> 5;
    int n = bid * 8 + nsub;
    int s0 = off[n], s1 = off[n + 1];
    float acc = 0.f;
    int j = s0;
    for (; j + 2 <= s1; j += 2) {
        ERec ra = rec[j], rb = rec[j + 1];
        u64 ka = ra.kid, kb = rb.kid;
        float xa = p.x0[ra.src], xb = p.x0[rb.src];
        float ma, mb;
        ma  = ra.q0.x * wlds[((int)( ka        & 255u)) * 32 + o];
        ma += ra.q0.y * wlds[((int)((ka >>  8) & 255u)) * 32 + o];
        ma += ra.q0.z * wlds[((int)((ka >> 16) & 255u)) * 32 + o];
        ma += ra.q0.w * wlds[((int)((ka >> 24) & 255u)) * 32 + o];
        ma += ra.q1.x * wlds[((int)((ka >> 32) & 255u)) * 32 + o];
        ma += ra.q1.y * wlds[((int)((ka >> 40) & 255u)) * 32 + o];
        ma += ra.q1.z * wlds[((int)((ka >> 48) & 255u)) * 32 + o];
        ma += ra.q1.w * wlds[((int)((ka >> 56) & 255u)) * 32 + o];
        mb  = rb.q0.x * wlds[((int)( kb        & 255u)) * 32 + o];
        mb += rb.q0.y * wlds[((int)((kb >>  8) & 255u)) * 32 + o];
        mb += rb.q0.z * wlds[((int)((kb >> 16) & 255u)) * 32 + o];
        mb += rb.q0.w * wlds[((int)((kb >> 24) & 255u)) * 32 + o];
        mb += rb.q1.x * wlds[((int)((kb >> 32) & 255u)) * 32 + o];
        mb += rb.q1.y * wlds[((int)((kb >> 40) & 255u)) * 32 + o];
        mb += rb.q1.z * wlds[((int)((kb >> 48) & 255u)) * 32 + o];
        mb += rb.q1.w * wlds[((int)((kb >> 56) & 255u)) * 32 + o];
        acc = fmaf(xa, ma, fmaf(xb, mb, acc));
    }
    if (j < s1) {
        ERec r = rec[j];
        u64 k8 = r.kid;
        float xv = p.x0[r.src];
        float m;
        m  = r.q0.x * wlds[((int)( k8        & 255u)) * 32 + o];
        m += r.q0.y * wlds[((int)((k8 >>  8) & 255u)) * 32 + o];
        m += r.q0.z * wlds[((int)((k8 >> 16) & 255u)) * 32 + o];
        m += r.q0.w * wlds[((int)((k8 >> 24) & 255u)) * 32 + o];
        m += r.q1.x * wlds[((int)((k8 >> 32) & 255u)) * 32 + o];
        m += r.q1.y * wlds[((int)((k8 >> 40) & 255u)) * 32 + o];
        m += r.q1.z * wlds[((int)((k8 >> 48) & 255u)) * 32 + o];
        m += r.q1.w * wlds[((int)((k8 >> 56) & 255u)) * 32 + o];
        acc = fmaf(xv, m, acc);
    }
    float dg = fmaxf((float)(s1 - s0), 1.f);
    float val = acc / dg + p.x0[n] * p.root1[o] + p.b1[o];
    val = eluf(val);
    atomicMax(&penc[(size_t)p.cl0[n] * 32 + o], enc_f(val));
}

// K5: gemm layer-2 (+ L2 scatter + W3/W4 transpose in tail blocks)
__global__ __launch_bounds__(256) void k_g2(P p) {
    __shared__ float smem[32 * 129];
    float* ws = p.ws;
    int bid = blockIdx.x;
    if (bid < NB_GEMM2) {
        gemm_unit<32>(bid, (unsigned*)(ws + A_PENC1), (unsigned short*)(ws + A_WT2),
                      (unsigned short*)(ws + A_Y), N1, KO2);
    } else if (bid < NB_GEMM2 + NB_SCAT2) {
        scat_unit(bid - NB_GEMM2, p.ps2, p.dst2, p.src2,
                  (int*)(ws + A_CUR2), (ERec*)(ws + A_REC2), E2);
    } else if (bid < NB_GEMM2 + NB_SCAT2 + K3) {
        wt_unit(p.W3, (unsigned short*)(ws + A_WT3), 64, 64, bid - NB_GEMM2 - NB_SCAT2, smem);
    } else {
        wt_unit(p.W4, (unsigned short*)(ws + A_WT4), 64, 128, bid - NB_GEMM2 - NB_SCAT2 - K3, smem);
    }
}

// K6: gather layer-2 (+ L3 scatter in tail blocks)
__global__ __launch_bounds__(256) void k_ga2(P p) {
    float* ws = p.ws;
    int bid = blockIdx.x;
    if (bid < NB_GA2) {
        gather_unit<32, 64>(bid, (unsigned short*)(ws + A_Y), (const ERec*)(ws + A_REC1),
                            (const int*)(ws + A_OFF1), (unsigned*)(ws + A_PENC1),
                            p.root2, p.b2, p.cl1, (unsigned*)(ws + A_PENC2));
    } else {
        scat_unit(bid - NB_GA2, p.ps3, p.dst3, p.src3,
                  (int*)(ws + A_CUR3), (ERec*)(ws + A_REC3), E3);
    }
}

// K7-K10: layer 3/4 gemm+gather
__global__ __launch_bounds__(256) void k_g3(P p) {
    gemm_unit<64>(blockIdx.x, (unsigned*)(p.ws + A_PENC2), (unsigned short*)(p.ws + A_WT3),
                  (unsigned short*)(p.ws + A_Y), N2, KO3);
}
__global__ __launch_bounds__(256) void k_ga3(P p) {
    gather_unit<64, 64>(blockIdx.x, (unsigned short*)(p.ws + A_Y), (const ERec*)(p.ws + A_REC2),
                        (const int*)(p.ws + A_OFF2), (unsigned*)(p.ws + A_PENC2),
                        p.root3, p.b3, p.cl2, (unsigned*)(p.ws + A_PENC3));
}
__global__ __launch_bounds__(256) void k_g4(P p) {
    gemm_unit<64>(blockIdx.x, (unsigned*)(p.ws + A_PENC3), (unsigned short*)(p.ws + A_WT4),
                  (unsigned short*)(p.ws + A_Y), N3, KO4);
}
__global__ __launch_bounds__(256) void k_ga4(P p) {
    gather_unit<64, 128>(blockIdx.x, (unsigned short*)(p.ws + A_Y), (const ERec*)(p.ws + A_REC3),
                         (const int*)(p.ws + A_OFF3), (unsigned*)(p.ws + A_PENC3),
                         p.root4, p.b4, p.cl3, (unsigned*)(p.ws + A_PENC4));
}

// K11: fused FC head: fc1 + ELU + fc2 + log_softmax, one block per batch row
__global__ __launch_bounds__(1024) void k_fc(P p) {
    __shared__ float xs[1024];
    __shared__ float part[4][257];
    __shared__ float h[256];
    __shared__ float l[10];
    __shared__ float red[2];
    int bq = blockIdx.x;
    int t = threadIdx.x;
    const unsigned* penc4 = (const unsigned*)(p.ws + A_PENC4);
    xs[t] = dec_fin(penc4[(size_t)bq * 1024 + t]);
    __syncthreads();
    int o = t & 255, sl = t >> 8;
    const float* wp = p.fc1w + (size_t)(sl * 256) * 256 + o;
    const float* xp = xs + sl * 256;
    float acc = 0.f;
#pragma unroll 8
    for (int k = 0; k < 256; ++k)
        acc = fmaf(xp[k], wp[(size_t)k * 256], acc);
    part[sl][o] = acc;
    __syncthreads();
    if (t < 256) {
        float v = part[0][t] + part[1][t] + part[2][t] + part[3][t] + p.fc1b[t];
        h[t] = eluf(v);
    }
    __syncthreads();
    if (t < 10) {
        float a2 = p.fc2b[t];
        for (int q = 0; q < 256; ++q)
            a2 = fmaf(h[q], p.fc2w[(size_t)q * 10 + t], a2);
        l[t] = a2;
    }
    __syncthreads();
    if (t == 0) {
        float m = l[0];
        for (int i = 1; i < 10; ++i) m = fmaxf(m, l[i]);
        float s = 0.f;
        for (int i = 0; i < 10; ++i) s += expf(l[i] - m);
        red[0] = m;
        red[1] = logf(s);
    }
    __syncthreads();
    if (t < 10) p.out[(size_t)bq * 10 + t] = l[t] - red[0] - red[1];
}

} // namespace

extern "C" void kernel_launch(void* const* d_in, const int* in_sizes, int n_in,
                              void* d_out, int out_size, void* d_ws, size_t ws_size,
                              hipStream_t stream) {
    P p;
    p.x0    = (const float*)d_in[0];
    p.ps0   = (const float*)d_in[1];
    p.ps1   = (const float*)d_in[2];
    p.ps2   = (const float*)d_in[3];
    p.ps3   = (const float*)d_in[4];
    p.W1    = (const float*)d_in[5];
    p.root1 = (const float*)d_in[6];
    p.b1    = (const float*)d_in[7];
    p.W2    = (const float*)d_in[8];
    p.root2 = (const float*)d_in[9];
    p.b2    = (const float*)d_in[10];
    p.W3    = (const float*)d_in[11];
    p.root3 = (const float*)d_in[12];
    p.b3    = (const float*)d_in[13];
    p.W4    = (const float*)d_in[14];
    p.root4 = (const float*)d_in[15];
    p.b4    = (const float*)d_in[16];
    p.fc1w  = (const float*)d_in[17];
    p.fc1b  = (const float*)d_in[18];
    p.fc2w  = (const float*)d_in[19];
    p.fc2b  = (const float*)d_in[20];
    p.src0 = (const int*)d_in[21];
    p.dst0 = (const int*)d_in[22];
    p.src1 = (const int*)d_in[23];
    p.dst1 = (const int*)d_in[24];
    p.src2 = (const int*)d_in[25];
    p.dst2 = (const int*)d_in[26];
    p.src3 = (const int*)d_in[27];
    p.dst3 = (const int*)d_in[28];
    p.cl0  = (const int*)d_in[29];
    p.cl1  = (const int*)d_in[30];
    p.cl2  = (const int*)d_in[31];
    p.cl3  = (const int*)d_in[32];
    p.ws = (float*)d_ws;
    p.out = (float*)d_out;

    hipMemsetAsync(p.ws + A_CUR0, 0, CUR_TOTAL * sizeof(int), stream);

    k_p1 <<<NB_HIST + K3, 256, 0, stream>>>(p);
    k_scan<<<4, 1024, 0, stream>>>(p);
    k_p2 <<<NB_SCAT0, 256, 0, stream>>>(p);
    k_l1 <<<NB_L1 + NB_SCAT1, 256, 0, stream>>>(p);
    k_g2 <<<NB_GEMM2 + NB_SCAT2 + 2 * K3, 256, 0, stream>>>(p);
    k_ga2<<<NB_GA2 + NB_SCAT3, 256, 0, stream>>>(p);
    k_g3 <<<NB_GEMM3, 256, 0, stream>>>(p);
    k_ga3<<<NB_GA3, 256, 0, stream>>>(p);
    k_g4 <<<NB_GEMM4, 256, 0, stream>>>(p);
    k_ga4<<<NB_GA4, 256, 0, stream>>>(p);
    k_fc <<<16, 1024, 0, stream>>>(p);
}